// Round 2
// baseline (64.029 us; speedup 1.0000x reference)
//
#include <hip/hip_runtime.h>
#include <math.h>

#define NQ 10

// One 256-thread block per batch element. 1024 amplitudes:
//   k = (w << 8) | (m << 6) | lane,  w = wave id (2 bits), m = reg idx (2 bits), lane (6 bits)
// Wire j <-> bit p = 9-j:
//   j=0,1 (bits 9,8): cross-wave -> combined 4x4 gate via LDS, once per layer
//   j=2,3 (bits 7,6): in-register pair update
//   j=4..9 (bits 5..0): cross-lane via __shfl_xor
__global__ __launch_bounds__(256, 8) void qlayer_kernel(
    const float* __restrict__ x,    // [B,10]
    const float* __restrict__ w1,   // [3,1,10,3]
    const float* __restrict__ w2,   // [1,10,3]
    float* __restrict__ out)        // [B,10]
{
    __shared__ float  g[40 * 8];          // 40 gate matrices, 8 floats each
    __shared__ float2 ex[2][4][4][64];    // [dbuf][w][m][lane] exchange, 16 KB
    __shared__ float  red[4][NQ];         // cross-wave output reduction

    const int t    = threadIdx.x;
    const int lane = t & 63;
    const int w    = t >> 6;
    const int b    = blockIdx.x;

    // ---- gate matrices (uniform across grid) computed once per block ----
    if (t < 40) {
        const int L = t / 10, j = t - L * 10;
        const float* wb = (L < 3) ? (w1 + L * 30 + j * 3) : (w2 + j * 3);
        const float phi = wb[0], th = wb[1], om = wb[2];
        float ct, st, epr, epi, emr, emi;
        __sincosf(0.5f * th, &st, &ct);
        __sincosf(-0.5f * (phi + om), &epi, &epr);   // ep = exp(-0.5i(phi+omega))
        __sincosf(-0.5f * (phi - om), &emi, &emr);   // em = exp(-0.5i(phi-omega))
        float* gp = &g[t * 8];
        gp[0] =  epr * ct; gp[1] =  epi * ct;        // M00
        gp[2] = -emr * st; gp[3] =  emi * st;        // M01 = -conj(em)*s
        gp[4] =  emr * st; gp[5] =  emi * st;        // M10
        gp[6] =  epr * ct; gp[7] = -epi * ct;        // M11 = conj(ep)*c
    }

    // ---- per-thread diagonals (reused across layers) ----
    float xv[NQ];
#pragma unroll
    for (int j = 0; j < NQ; ++j) xv[j] = x[b * NQ + j];
    float S = 0.f;
#pragma unroll
    for (int j = 0; j < NQ; ++j) S += xv[j];
    float Tlo = 0.f;
#pragma unroll
    for (int p = 0; p < 6; ++p) Tlo += ((lane >> p) & 1) ? xv[9 - p] : 0.f;
    const float Twv  = ((w & 1) ? xv[1] : 0.f) + ((w & 2) ? xv[0] : 0.f);
    const float base = -0.5f * S + Tlo + Twv;

    // phase diagonal (same all 3 entangling layers) folded with CZ sign
    float dr[4], di[4], czf[4];
#pragma unroll
    for (int m = 0; m < 4; ++m) {
        const int k  = (w << 8) | (m << 6) | lane;
        const int kr = ((k << 1) | (k >> 9)) & 1023;
        const float cz = (__popc(k & kr) & 1) ? -1.f : 1.f;
        czf[m] = cz;
        const float ang = base + ((m & 1) ? xv[3] : 0.f) + ((m & 2) ? xv[2] : 0.f);
        float sn, cn;
        __sincosf(ang, &sn, &cn);
        dr[m] = cn * cz;
        di[m] = sn * cz;
    }

    // ---- state |0...0> ----
    float sr[4], si[4];
#pragma unroll
    for (int m = 0; m < 4; ++m) { sr[m] = 0.f; si[m] = 0.f; }
    if (t == 0) sr[0] = 1.f;

    __syncthreads();   // gate matrices ready

#pragma unroll 1
    for (int L = 0; L < 4; ++L) {
        const float* gl = &g[L * 80];

        // shfl gates: wires 4..9 (lane bits 5..0). A = self coef, B = partner coef.
#pragma unroll
        for (int j = 4; j < NQ; ++j) {
            const float* gp = &gl[j * 8];
            const int p = 9 - j;
            const bool hi = (lane >> p) & 1;
            const float Ar = hi ? gp[6] : gp[0];
            const float Ai = hi ? gp[7] : gp[1];
            const float Br = hi ? gp[4] : gp[2];
            const float Bi = hi ? gp[5] : gp[3];
#pragma unroll
            for (int m = 0; m < 4; ++m) {
                const float qr = __shfl_xor(sr[m], 1 << p, 64);
                const float qi = __shfl_xor(si[m], 1 << p, 64);
                const float r0 = sr[m], i0 = si[m];
                sr[m] = Ar * r0 - Ai * i0 + Br * qr - Bi * qi;
                si[m] = Ar * i0 + Ai * r0 + Br * qi + Bi * qr;
            }
        }

        // register gates: wire 2 (m-bit 1), wire 3 (m-bit 0)
#pragma unroll
        for (int j = 2; j < 4; ++j) {
            const float* gp = &gl[j * 8];
            const int mb = (j == 2) ? 2 : 1;
#pragma unroll
            for (int m0 = 0; m0 < 4; ++m0) {
                if (m0 & mb) continue;
                const int m1 = m0 | mb;
                const float a0r = sr[m0], a0i = si[m0];
                const float a1r = sr[m1], a1i = si[m1];
                sr[m0] = gp[0]*a0r - gp[1]*a0i + gp[2]*a1r - gp[3]*a1i;
                si[m0] = gp[0]*a0i + gp[1]*a0r + gp[2]*a1i + gp[3]*a1r;
                sr[m1] = gp[4]*a0r - gp[5]*a0i + gp[6]*a1r - gp[7]*a1i;
                si[m1] = gp[4]*a0i + gp[5]*a0r + gp[6]*a1i + gp[7]*a1r;
            }
        }

        // combined cross-wave gate: wires 0,1 (bits 9,8). T[w][w'] = M0[w1][w1']*M1[w0][w0'].
        {
            const float* g0 = &gl[0];
            const float* g1 = &gl[8];
            const int w1b = w >> 1, w0b = w & 1;
            const float a0r = w1b ? g0[4] : g0[0], a0i = w1b ? g0[5] : g0[1]; // M0[w1b][0]
            const float a1r = w1b ? g0[6] : g0[2], a1i = w1b ? g0[7] : g0[3]; // M0[w1b][1]
            const float b0r = w0b ? g1[4] : g1[0], b0i = w0b ? g1[5] : g1[1]; // M1[w0b][0]
            const float b1r = w0b ? g1[6] : g1[2], b1i = w0b ? g1[7] : g1[3]; // M1[w0b][1]
            float Tr[4], Ti[4];
            Tr[0] = a0r*b0r - a0i*b0i;  Ti[0] = a0r*b0i + a0i*b0r;
            Tr[1] = a0r*b1r - a0i*b1i;  Ti[1] = a0r*b1i + a0i*b1r;
            Tr[2] = a1r*b0r - a1i*b0i;  Ti[2] = a1r*b0i + a1i*b0r;
            Tr[3] = a1r*b1r - a1i*b1i;  Ti[3] = a1r*b1i + a1i*b1r;

            const int buf = L & 1;
#pragma unroll
            for (int m = 0; m < 4; ++m)
                ex[buf][w][m][lane] = make_float2(sr[m], si[m]);
            __syncthreads();
#pragma unroll
            for (int m = 0; m < 4; ++m) {
                float nr = 0.f, ni = 0.f;
#pragma unroll
                for (int wp = 0; wp < 4; ++wp) {
                    const float2 a = ex[buf][wp][m][lane];
                    nr += Tr[wp]*a.x - Ti[wp]*a.y;
                    ni += Tr[wp]*a.y + Ti[wp]*a.x;
                }
                sr[m] = nr; si[m] = ni;
            }
        }

        // diagonal: CZ ring (+ data-reupload phase for entangling layers)
        if (L < 3) {
#pragma unroll
            for (int m = 0; m < 4; ++m) {
                const float r = sr[m], ii = si[m];
                sr[m] = r * dr[m] - ii * di[m];
                si[m] = r * di[m] + ii * dr[m];
            }
        } else {
#pragma unroll
            for (int m = 0; m < 4; ++m) { sr[m] *= czf[m]; si[m] *= czf[m]; }
        }
    }

    // ---- <Z_j> ----
    float acc[NQ];
#pragma unroll
    for (int j = 0; j < NQ; ++j) acc[j] = 0.f;
#pragma unroll
    for (int m = 0; m < 4; ++m) {
        const float pk = sr[m]*sr[m] + si[m]*si[m];
        const int k = (w << 8) | (m << 6) | lane;
#pragma unroll
        for (int j = 0; j < NQ; ++j)
            acc[j] += ((k >> (9 - j)) & 1) ? -pk : pk;
    }
#pragma unroll
    for (int j = 0; j < NQ; ++j) {
        float v = acc[j];
#pragma unroll
        for (int d = 32; d > 0; d >>= 1) v += __shfl_xor(v, d, 64);
        if (lane == 0) red[w][j] = v;
    }
    __syncthreads();
    if (t < NQ)
        out[b * NQ + t] = red[0][t] + red[1][t] + red[2][t] + red[3][t];
}

extern "C" void kernel_launch(void* const* d_in, const int* in_sizes, int n_in,
                              void* d_out, int out_size, void* d_ws, size_t ws_size,
                              hipStream_t stream) {
    const float* x  = (const float*)d_in[0];   // [B,10] f32
    const float* w1 = (const float*)d_in[1];   // [3,1,10,3] f32
    const float* w2 = (const float*)d_in[2];   // [1,10,3] f32
    float* out = (float*)d_out;                // [B,10] f32
    const int B = in_sizes[0] / NQ;            // 2048
    qlayer_kernel<<<B, 256, 0, stream>>>(x, w1, w2, out);
}

// Round 3
// 44.285 us; speedup vs baseline: 1.4459x; 1.4459x over previous
//
#include <hip/hip_runtime.h>
#include <math.h>

#define NQ 10

// One 256-thread block per batch element. 1024 amplitudes:
//   k = (w << 8) | (m << 6) | lane,  w = wave id (2 bits), m = reg idx (2 bits), lane (6 bits)
// Wire j <-> bit p = 9-j:
//   j=0,1 (bits 9,8): cross-wave -> combined 4x4 gate via LDS, once per layer
//   j=2,3 (bits 7,6): in-register pair update
//   j=4..9 (bits 5..0): cross-lane via __shfl_xor
// launch_bounds(256,4): VGPR cap 128. (256,8) capped at 64 and spilled 170MB
// of scratch to HBM per dispatch (round-2 regression).
__global__ __launch_bounds__(256, 4) void qlayer_kernel(
    const float* __restrict__ x,    // [B,10]
    const float* __restrict__ w1,   // [3,1,10,3]
    const float* __restrict__ w2,   // [1,10,3]
    float* __restrict__ out)        // [B,10]
{
    __shared__ float  g[40 * 8];          // 40 gate matrices, 8 floats each
    __shared__ float2 ex[2][4][4][64];    // [dbuf][w][m][lane] exchange, 16 KB
    __shared__ float  red[4][NQ];         // cross-wave output reduction

    const int t    = threadIdx.x;
    const int lane = t & 63;
    const int w    = t >> 6;
    const int b    = blockIdx.x;

    // ---- gate matrices (uniform across grid) computed once per block ----
    if (t < 40) {
        const int L = t / 10, j = t - L * 10;
        const float* wb = (L < 3) ? (w1 + L * 30 + j * 3) : (w2 + j * 3);
        const float phi = wb[0], th = wb[1], om = wb[2];
        float ct, st, epr, epi, emr, emi;
        __sincosf(0.5f * th, &st, &ct);
        __sincosf(-0.5f * (phi + om), &epi, &epr);   // ep = exp(-0.5i(phi+omega))
        __sincosf(-0.5f * (phi - om), &emi, &emr);   // em = exp(-0.5i(phi-omega))
        float* gp = &g[t * 8];
        gp[0] =  epr * ct; gp[1] =  epi * ct;        // M00
        gp[2] = -emr * st; gp[3] =  emi * st;        // M01 = -conj(em)*s
        gp[4] =  emr * st; gp[5] =  emi * st;        // M10
        gp[6] =  epr * ct; gp[7] = -epi * ct;        // M11 = conj(ep)*c
    }

    // ---- per-thread diagonals (reused across layers) ----
    float xv[NQ];
#pragma unroll
    for (int j = 0; j < NQ; ++j) xv[j] = x[b * NQ + j];
    float S = 0.f;
#pragma unroll
    for (int j = 0; j < NQ; ++j) S += xv[j];
    float Tlo = 0.f;
#pragma unroll
    for (int p = 0; p < 6; ++p) Tlo += ((lane >> p) & 1) ? xv[9 - p] : 0.f;
    const float Twv  = ((w & 1) ? xv[1] : 0.f) + ((w & 2) ? xv[0] : 0.f);
    const float base = -0.5f * S + Tlo + Twv;

    // phase diagonal (same all 3 entangling layers) folded with CZ sign
    float dr[4], di[4], czf[4];
#pragma unroll
    for (int m = 0; m < 4; ++m) {
        const int k  = (w << 8) | (m << 6) | lane;
        const int kr = ((k << 1) | (k >> 9)) & 1023;
        const float cz = (__popc(k & kr) & 1) ? -1.f : 1.f;
        czf[m] = cz;
        const float ang = base + ((m & 1) ? xv[3] : 0.f) + ((m & 2) ? xv[2] : 0.f);
        float sn, cn;
        __sincosf(ang, &sn, &cn);
        dr[m] = cn * cz;
        di[m] = sn * cz;
    }

    // ---- state |0...0> ----
    float sr[4], si[4];
#pragma unroll
    for (int m = 0; m < 4; ++m) { sr[m] = 0.f; si[m] = 0.f; }
    if (t == 0) sr[0] = 1.f;

    __syncthreads();   // gate matrices ready

#pragma unroll 1
    for (int L = 0; L < 4; ++L) {
        const float* gl = &g[L * 80];

        // shfl gates: wires 4..9 (lane bits 5..0). A = self coef, B = partner coef.
#pragma unroll
        for (int j = 4; j < NQ; ++j) {
            const float* gp = &gl[j * 8];
            const int p = 9 - j;
            const bool hi = (lane >> p) & 1;
            const float Ar = hi ? gp[6] : gp[0];
            const float Ai = hi ? gp[7] : gp[1];
            const float Br = hi ? gp[4] : gp[2];
            const float Bi = hi ? gp[5] : gp[3];
#pragma unroll
            for (int m = 0; m < 4; ++m) {
                const float qr = __shfl_xor(sr[m], 1 << p, 64);
                const float qi = __shfl_xor(si[m], 1 << p, 64);
                const float r0 = sr[m], i0 = si[m];
                sr[m] = Ar * r0 - Ai * i0 + Br * qr - Bi * qi;
                si[m] = Ar * i0 + Ai * r0 + Br * qi + Bi * qr;
            }
        }

        // register gates: wire 2 (m-bit 1), wire 3 (m-bit 0)
#pragma unroll
        for (int j = 2; j < 4; ++j) {
            const float* gp = &gl[j * 8];
            const int mb = (j == 2) ? 2 : 1;
#pragma unroll
            for (int m0 = 0; m0 < 4; ++m0) {
                if (m0 & mb) continue;
                const int m1 = m0 | mb;
                const float a0r = sr[m0], a0i = si[m0];
                const float a1r = sr[m1], a1i = si[m1];
                sr[m0] = gp[0]*a0r - gp[1]*a0i + gp[2]*a1r - gp[3]*a1i;
                si[m0] = gp[0]*a0i + gp[1]*a0r + gp[2]*a1i + gp[3]*a1r;
                sr[m1] = gp[4]*a0r - gp[5]*a0i + gp[6]*a1r - gp[7]*a1i;
                si[m1] = gp[4]*a0i + gp[5]*a0r + gp[6]*a1i + gp[7]*a1r;
            }
        }

        // combined cross-wave gate: wires 0,1 (bits 9,8). T[w][w'] = M0[w1][w1']*M1[w0][w0'].
        {
            const float* g0 = &gl[0];
            const float* g1 = &gl[8];
            const int w1b = w >> 1, w0b = w & 1;
            const float a0r = w1b ? g0[4] : g0[0], a0i = w1b ? g0[5] : g0[1]; // M0[w1b][0]
            const float a1r = w1b ? g0[6] : g0[2], a1i = w1b ? g0[7] : g0[3]; // M0[w1b][1]
            const float b0r = w0b ? g1[4] : g1[0], b0i = w0b ? g1[5] : g1[1]; // M1[w0b][0]
            const float b1r = w0b ? g1[6] : g1[2], b1i = w0b ? g1[7] : g1[3]; // M1[w0b][1]
            float Tr[4], Ti[4];
            Tr[0] = a0r*b0r - a0i*b0i;  Ti[0] = a0r*b0i + a0i*b0r;
            Tr[1] = a0r*b1r - a0i*b1i;  Ti[1] = a0r*b1i + a0i*b1r;
            Tr[2] = a1r*b0r - a1i*b0i;  Ti[2] = a1r*b0i + a1i*b0r;
            Tr[3] = a1r*b1r - a1i*b1i;  Ti[3] = a1r*b1i + a1i*b1r;

            const int buf = L & 1;
#pragma unroll
            for (int m = 0; m < 4; ++m)
                ex[buf][w][m][lane] = make_float2(sr[m], si[m]);
            __syncthreads();
#pragma unroll
            for (int m = 0; m < 4; ++m) {
                float nr = 0.f, ni = 0.f;
#pragma unroll
                for (int wp = 0; wp < 4; ++wp) {
                    const float2 a = ex[buf][wp][m][lane];
                    nr += Tr[wp]*a.x - Ti[wp]*a.y;
                    ni += Tr[wp]*a.y + Ti[wp]*a.x;
                }
                sr[m] = nr; si[m] = ni;
            }
        }

        // diagonal: CZ ring (+ data-reupload phase for entangling layers)
        if (L < 3) {
#pragma unroll
            for (int m = 0; m < 4; ++m) {
                const float r = sr[m], ii = si[m];
                sr[m] = r * dr[m] - ii * di[m];
                si[m] = r * di[m] + ii * dr[m];
            }
        } else {
#pragma unroll
            for (int m = 0; m < 4; ++m) { sr[m] *= czf[m]; si[m] *= czf[m]; }
        }
    }

    // ---- <Z_j> ----
    float acc[NQ];
#pragma unroll
    for (int j = 0; j < NQ; ++j) acc[j] = 0.f;
#pragma unroll
    for (int m = 0; m < 4; ++m) {
        const float pk = sr[m]*sr[m] + si[m]*si[m];
        const int k = (w << 8) | (m << 6) | lane;
#pragma unroll
        for (int j = 0; j < NQ; ++j)
            acc[j] += ((k >> (9 - j)) & 1) ? -pk : pk;
    }
#pragma unroll
    for (int j = 0; j < NQ; ++j) {
        float v = acc[j];
#pragma unroll
        for (int d = 32; d > 0; d >>= 1) v += __shfl_xor(v, d, 64);
        if (lane == 0) red[w][j] = v;
    }
    __syncthreads();
    if (t < NQ)
        out[b * NQ + t] = red[0][t] + red[1][t] + red[2][t] + red[3][t];
}

extern "C" void kernel_launch(void* const* d_in, const int* in_sizes, int n_in,
                              void* d_out, int out_size, void* d_ws, size_t ws_size,
                              hipStream_t stream) {
    const float* x  = (const float*)d_in[0];   // [B,10] f32
    const float* w1 = (const float*)d_in[1];   // [3,1,10,3] f32
    const float* w2 = (const float*)d_in[2];   // [1,10,3] f32
    float* out = (float*)d_out;                // [B,10] f32
    const int B = in_sizes[0] / NQ;            // 2048
    qlayer_kernel<<<B, 256, 0, stream>>>(x, w1, w2, out);
}

// Round 4
// 37.871 us; speedup vs baseline: 1.6907x; 1.1694x over previous
//
#include <hip/hip_runtime.h>
#include <math.h>

#define NQ 10

typedef float v2f __attribute__((ext_vector_type(2)));

static __device__ __forceinline__ v2f mk2(float a, float b) { v2f r; r.x = a; r.y = b; return r; }
static __device__ __forceinline__ v2f sp2(float a)          { v2f r; r.x = a; r.y = a; return r; }
static __device__ __forceinline__ v2f pkfma(v2f a, v2f b, v2f c) { return __builtin_elementwise_fma(a, b, c); }
static __device__ __forceinline__ v2f shfl2(v2f v, int msk) {
    return mk2(__shfl_xor(v.x, msk, 64), __shfl_xor(v.y, msk, 64));
}

// One 256-thread block per batch element. 1024 amplitudes:
//   k = (w << 8) | (m << 6) | lane,  w = wave (2b), m = reg idx (2b), lane (6b)
// State packed over m: sr01={m0,m1}, sr23={m2,m3} (v2f -> v_pk_fma_f32, 2x FP32 rate).
//   wires 0,1 (bits 9,8): cross-wave 4x4 gate via LDS (elementwise in m -> packed)
//   wire  2   (bit 7 = m-bit 1): pairs sr01<->sr23, elementwise -> packed
//   wire  3   (bit 6 = m-bit 0): pairs within a packed reg -> scalar
//   wires 4..9 (lane bits 5..0): __shfl_xor, elementwise in m -> packed
__global__ __launch_bounds__(256, 4) void qlayer_kernel(
    const float* __restrict__ x,    // [B,10]
    const float* __restrict__ w1,   // [3,1,10,3]
    const float* __restrict__ w2,   // [1,10,3]
    float* __restrict__ out)        // [B,10]
{
    __shared__ float g[40 * 8];           // 40 gate matrices {M00,M01,M10,M11} (r,i)
    __shared__ v2f   ex[2][4][4][64];     // [dbuf][w][{sr01,si01,sr23,si23}][lane], 16 KB
    __shared__ float red[4][NQ];

    const int t    = threadIdx.x;
    const int lane = t & 63;
    const int w    = t >> 6;
    const int b    = blockIdx.x;

    // ---- gate matrices (uniform across grid): once per block ----
    if (t < 40) {
        const int L = t / 10, j = t - L * 10;
        const float* wb = (L < 3) ? (w1 + L * 30 + j * 3) : (w2 + j * 3);
        const float phi = wb[0], th = wb[1], om = wb[2];
        float ct, st, epr, epi, emr, emi;
        __sincosf(0.5f * th, &st, &ct);
        __sincosf(-0.5f * (phi + om), &epi, &epr);
        __sincosf(-0.5f * (phi - om), &emi, &emr);
        float* gp = &g[t * 8];
        gp[0] =  epr * ct; gp[1] =  epi * ct;        // M00
        gp[2] = -emr * st; gp[3] =  emi * st;        // M01 = -conj(em)*s
        gp[4] =  emr * st; gp[5] =  emi * st;        // M10
        gp[6] =  epr * ct; gp[7] = -epi * ct;        // M11 = conj(ep)*c
    }

    // ---- per-thread reusable diagonals ----
    float xv[NQ];
#pragma unroll
    for (int j = 0; j < NQ; ++j) xv[j] = x[b * NQ + j];
    float S = 0.f;
#pragma unroll
    for (int j = 0; j < NQ; ++j) S += xv[j];
    float Tlo = 0.f;
#pragma unroll
    for (int p = 0; p < 6; ++p) Tlo += ((lane >> p) & 1) ? xv[9 - p] : 0.f;
    const float Twv  = ((w & 1) ? xv[1] : 0.f) + ((w & 2) ? xv[0] : 0.f);
    const float base = -0.5f * S + Tlo + Twv;

    // CZ signs per m (k = w<<8 | m<<6 | lane)
    float cz[4];
#pragma unroll
    for (int m = 0; m < 4; ++m) {
        const int k  = (w << 8) | (m << 6) | lane;
        const int kr = ((k << 1) | (k >> 9)) & 1023;
        cz[m] = (__popc(k & kr) & 1) ? -1.f : 1.f;
    }
    const v2f cz01 = mk2(cz[0], cz[1]);
    const v2f cz23 = mk2(cz[2], cz[3]);

    // phase diagonal e^{i(base + m&1?x3 + m&2?x2)} via complex chain (3 sincos, not 4)
    float cb, sb, c2, s2, c3, s3;
    __sincosf(base,  &sb, &cb);
    __sincosf(xv[2], &s2, &c2);
    __sincosf(xv[3], &s3, &c3);
    const float d1r = cb * c3 - sb * s3, d1i = cb * s3 + sb * c3;   // E0*E3
    const float d2r = cb * c2 - sb * s2, d2i = cb * s2 + sb * c2;   // E0*E2
    const float d3r = d2r * c3 - d2i * s3, d3i = d2r * s3 + d2i * c3; // E0*E2*E3
    const v2f dr01 = mk2(cb  * cz[0], d1r * cz[1]);
    const v2f di01 = mk2(sb  * cz[0], d1i * cz[1]);
    const v2f dr23 = mk2(d2r * cz[2], d3r * cz[3]);
    const v2f di23 = mk2(d2i * cz[2], d3i * cz[3]);

    // ---- state |0...0> ----
    v2f sr01 = sp2(0.f), si01 = sp2(0.f), sr23 = sp2(0.f), si23 = sp2(0.f);
    if (t == 0) sr01.x = 1.f;

    __syncthreads();   // gate matrices ready

#pragma unroll 1
    for (int L = 0; L < 4; ++L) {
        const float* gl = &g[L * 80];

        // ---- shfl gates: wires 4..9 (lane bits 5..0), packed over m ----
#pragma unroll
        for (int j = 4; j < NQ; ++j) {
            const float4 A = *(const float4*)(gl + j * 8);      // M00r,M00i,M01r,M01i
            const float4 Bq = *(const float4*)(gl + j * 8 + 4); // M10r,M10i,M11r,M11i
            const int p = 9 - j;
            const bool hi = (lane >> p) & 1;
            const v2f Ar  = sp2(hi ? Bq.z : A.x);
            const v2f nAi = sp2(hi ? -Bq.w : -A.y);
            const v2f Ai  = sp2(hi ? Bq.w : A.y);
            const v2f Br  = sp2(hi ? Bq.x : A.z);
            const v2f nBi = sp2(hi ? -Bq.y : -A.w);
            const v2f Bi  = sp2(hi ? Bq.y : A.w);
            const int msk = 1 << p;
            const v2f qr01 = shfl2(sr01, msk), qi01 = shfl2(si01, msk);
            const v2f qr23 = shfl2(sr23, msk), qi23 = shfl2(si23, msk);
            v2f tr, ti;
            tr = pkfma(nBi, qi01, Br * qr01); tr = pkfma(nAi, si01, tr); tr = pkfma(Ar, sr01, tr);
            ti = pkfma(Bi,  qr01, Br * qi01); ti = pkfma(Ai,  sr01, ti); ti = pkfma(Ar, si01, ti);
            sr01 = tr; si01 = ti;
            tr = pkfma(nBi, qi23, Br * qr23); tr = pkfma(nAi, si23, tr); tr = pkfma(Ar, sr23, tr);
            ti = pkfma(Bi,  qr23, Br * qi23); ti = pkfma(Ai,  sr23, ti); ti = pkfma(Ar, si23, ti);
            sr23 = tr; si23 = ti;
        }

        // ---- wire 2 (m-bit 1): pairs {m0,m1}<->{m2,m3}, fully packed ----
        {
            const float4 A = *(const float4*)(gl + 2 * 8);
            const float4 Bq = *(const float4*)(gl + 2 * 8 + 4);
            const v2f g0 = sp2(A.x), g1 = sp2(A.y), g2 = sp2(A.z), g3 = sp2(A.w);
            const v2f g4 = sp2(Bq.x), g5 = sp2(Bq.y), g6 = sp2(Bq.z), g7 = sp2(Bq.w);
            const v2f a0r = sr01, a0i = si01, a1r = sr23, a1i = si23;
            sr01 = pkfma(g0, a0r, pkfma(-g1, a0i, pkfma(g2, a1r, -g3 * a1i)));
            si01 = pkfma(g0, a0i, pkfma( g1, a0r, pkfma(g2, a1i,  g3 * a1r)));
            sr23 = pkfma(g4, a0r, pkfma(-g5, a0i, pkfma(g6, a1r, -g7 * a1i)));
            si23 = pkfma(g4, a0i, pkfma( g5, a0r, pkfma(g6, a1i,  g7 * a1r)));
        }

        // ---- wire 3 (m-bit 0): pairs within packed regs, scalar ----
        {
            const float4 A = *(const float4*)(gl + 3 * 8);
            const float4 Bq = *(const float4*)(gl + 3 * 8 + 4);
            {
                const float a0r = sr01.x, a0i = si01.x, a1r = sr01.y, a1i = si01.y;
                sr01.x = A.x*a0r - A.y*a0i + A.z*a1r - A.w*a1i;
                si01.x = A.x*a0i + A.y*a0r + A.z*a1i + A.w*a1r;
                sr01.y = Bq.x*a0r - Bq.y*a0i + Bq.z*a1r - Bq.w*a1i;
                si01.y = Bq.x*a0i + Bq.y*a0r + Bq.z*a1i + Bq.w*a1r;
            }
            {
                const float a0r = sr23.x, a0i = si23.x, a1r = sr23.y, a1i = si23.y;
                sr23.x = A.x*a0r - A.y*a0i + A.z*a1r - A.w*a1i;
                si23.x = A.x*a0i + A.y*a0r + A.z*a1i + A.w*a1r;
                sr23.y = Bq.x*a0r - Bq.y*a0i + Bq.z*a1r - Bq.w*a1i;
                si23.y = Bq.x*a0i + Bq.y*a0r + Bq.z*a1i + Bq.w*a1r;
            }
        }

        // ---- cross-wave combined gate (wires 0,1): T[w][w'] = M0[w1][w1']*M1[w0][w0'] ----
        {
            const float4 A0 = *(const float4*)(gl);
            const float4 B0 = *(const float4*)(gl + 4);
            const float4 A1 = *(const float4*)(gl + 8);
            const float4 B1 = *(const float4*)(gl + 12);
            const int w1b = w >> 1, w0b = w & 1;
            const float a0r = w1b ? B0.x : A0.x, a0i = w1b ? B0.y : A0.y; // M0[w1b][0]
            const float a1r = w1b ? B0.z : A0.z, a1i = w1b ? B0.w : A0.w; // M0[w1b][1]
            const float b0r = w0b ? B1.x : A1.x, b0i = w0b ? B1.y : A1.y; // M1[w0b][0]
            const float b1r = w0b ? B1.z : A1.z, b1i = w0b ? B1.w : A1.w; // M1[w0b][1]
            float Tr[4], Ti[4];
            Tr[0] = a0r*b0r - a0i*b0i;  Ti[0] = a0r*b0i + a0i*b0r;
            Tr[1] = a0r*b1r - a0i*b1i;  Ti[1] = a0r*b1i + a0i*b1r;
            Tr[2] = a1r*b0r - a1i*b0i;  Ti[2] = a1r*b0i + a1i*b0r;
            Tr[3] = a1r*b1r - a1i*b1i;  Ti[3] = a1r*b1i + a1i*b1r;

            const int buf = L & 1;
            ex[buf][w][0][lane] = sr01;
            ex[buf][w][1][lane] = si01;
            ex[buf][w][2][lane] = sr23;
            ex[buf][w][3][lane] = si23;
            __syncthreads();
            v2f nr01 = sp2(0.f), ni01 = sp2(0.f), nr23 = sp2(0.f), ni23 = sp2(0.f);
#pragma unroll
            for (int wp = 0; wp < 4; ++wp) {
                const v2f Trp = sp2(Tr[wp]), Tip = sp2(Ti[wp]), nTip = sp2(-Ti[wp]);
                const v2f ar01 = ex[buf][wp][0][lane];
                const v2f ai01 = ex[buf][wp][1][lane];
                const v2f ar23 = ex[buf][wp][2][lane];
                const v2f ai23 = ex[buf][wp][3][lane];
                nr01 = pkfma(Trp, ar01, pkfma(nTip, ai01, nr01));
                ni01 = pkfma(Trp, ai01, pkfma(Tip,  ar01, ni01));
                nr23 = pkfma(Trp, ar23, pkfma(nTip, ai23, nr23));
                ni23 = pkfma(Trp, ai23, pkfma(Tip,  ar23, ni23));
            }
            sr01 = nr01; si01 = ni01; sr23 = nr23; si23 = ni23;
        }

        // ---- diagonal ----
        if (L < 3) {
            v2f tmp;
            tmp  = pkfma(sr01, dr01, -(si01 * di01));
            si01 = pkfma(sr01, di01,   si01 * dr01);
            sr01 = tmp;
            tmp  = pkfma(sr23, dr23, -(si23 * di23));
            si23 = pkfma(sr23, di23,   si23 * dr23);
            sr23 = tmp;
        } else {
            sr01 *= cz01; si01 *= cz01; sr23 *= cz23; si23 *= cz23;
        }
    }

    // ---- <Z_j> ----
    const v2f p01 = pkfma(sr01, sr01, si01 * si01);
    const v2f p23 = pkfma(sr23, sr23, si23 * si23);
    const float s01 = p01.x + p01.y, s23 = p23.x + p23.y;
    const float tot = s01 + s23;
    float t9[9];
    t9[0] = tot;                                   // -> j=0,1 (w signs at write)
    t9[1] = s01 - s23;                             // j=2 (m-bit 1)
    t9[2] = (p01.x - p01.y) + (p23.x - p23.y);     // j=3 (m-bit 0)
#pragma unroll
    for (int p = 0; p < 6; ++p)                    // lane-bit wires j=9-p
        t9[3 + p] = ((lane >> p) & 1) ? -tot : tot;
#pragma unroll
    for (int i = 0; i < 9; ++i) {
        float v = t9[i];
#pragma unroll
        for (int d = 32; d > 0; d >>= 1) v += __shfl_xor(v, d, 64);
        t9[i] = v;
    }
    if (lane == 0) {
        red[w][0] = (w & 2) ? -t9[0] : t9[0];
        red[w][1] = (w & 1) ? -t9[0] : t9[0];
        red[w][2] = t9[1];
        red[w][3] = t9[2];
#pragma unroll
        for (int p = 0; p < 6; ++p) red[w][9 - p] = t9[3 + p];
    }
    __syncthreads();
    if (t < NQ)
        out[b * NQ + t] = red[0][t] + red[1][t] + red[2][t] + red[3][t];
}

extern "C" void kernel_launch(void* const* d_in, const int* in_sizes, int n_in,
                              void* d_out, int out_size, void* d_ws, size_t ws_size,
                              hipStream_t stream) {
    const float* x  = (const float*)d_in[0];   // [B,10] f32
    const float* w1 = (const float*)d_in[1];   // [3,1,10,3] f32
    const float* w2 = (const float*)d_in[2];   // [1,10,3] f32
    float* out = (float*)d_out;                // [B,10] f32
    const int B = in_sizes[0] / NQ;            // 2048
    qlayer_kernel<<<B, 256, 0, stream>>>(x, w1, w2, out);
}

// Round 5
// 28.743 us; speedup vs baseline: 2.2277x; 1.3176x over previous
//
#include <hip/hip_runtime.h>
#include <math.h>

#define NQ 10

typedef float v2f __attribute__((ext_vector_type(2)));

static __device__ __forceinline__ v2f mk2(float a, float b) { v2f r; r.x = a; r.y = b; return r; }
static __device__ __forceinline__ v2f sp2(float a)          { v2f r; r.x = a; r.y = a; return r; }
static __device__ __forceinline__ v2f pkfma(v2f a, v2f b, v2f c) { return __builtin_elementwise_fma(a, b, c); }
static __device__ __forceinline__ v2f shfl2(v2f v, int m) {
    return mk2(__shfl_xor(v.x, m, 64), __shfl_xor(v.y, m, 64));
}

// One WAVE per batch element (4 elements per 256-thread block; gate table shared).
// 1024 amplitudes: k = m*64 + lane; m = 2*p + e (p = v2f reg 0..7, e = lane within pack).
// Wire j acts on bit 9-j:
//   j=0,1,2 (m bits 3,2,1 = p bits 2,1,0): packed register-pair gates
//   j=3     (m bit 0 = e):                intra-v2f gate via coefficient-swapped pkfma
//   j=4..9  (lane bits 5..0):             __shfl_xor gates, packed over m
// No barriers after gate setup; no cross-wave exchange. Final CZ dropped (|psi|^2
// invariant under the +-1 diagonal).
__global__ void qlayer_kernel(
    const float* __restrict__ x,    // [B,10]
    const float* __restrict__ w1,   // [3,1,10,3]
    const float* __restrict__ w2,   // [1,10,3]
    float* __restrict__ out)        // [B,10]
{
    __shared__ float g[40 * 8];     // 40 gate matrices {M00,M01,M10,M11}(r,i)

    const int t    = threadIdx.x;
    const int lane = t & 63;
    const int w    = t >> 6;
    const int b    = (blockIdx.x << 2) + w;

    // ---- gate matrices (uniform across grid): once per block ----
    if (t < 40) {
        const int L = t / 10, j = t - L * 10;
        const float* wb = (L < 3) ? (w1 + L * 30 + j * 3) : (w2 + j * 3);
        const float phi = wb[0], th = wb[1], om = wb[2];
        float ct, st, epr, epi, emr, emi;
        __sincosf(0.5f * th, &st, &ct);
        __sincosf(-0.5f * (phi + om), &epi, &epr);
        __sincosf(-0.5f * (phi - om), &emi, &emr);
        float* gp = &g[t * 8];
        gp[0] =  epr * ct; gp[1] =  epi * ct;        // M00
        gp[2] = -emr * st; gp[3] =  emi * st;        // M01 = -conj(em)*s
        gp[4] =  emr * st; gp[5] =  emi * st;        // M10
        gp[6] =  epr * ct; gp[7] = -epi * ct;        // M11 = conj(ep)*c
    }

    // ---- per-lane prologue ----
    float xv[NQ];
#pragma unroll
    for (int j = 0; j < NQ; ++j) xv[j] = x[b * NQ + j];
    float S = 0.f;
#pragma unroll
    for (int j = 0; j < NQ; ++j) S += xv[j];
    float Tlo = 0.f;
#pragma unroll
    for (int p = 0; p < 6; ++p) Tlo += ((lane >> p) & 1) ? xv[9 - p] : 0.f;
    const float base = -0.5f * S + Tlo;

    // CZ sign per m (k = m<<6 | lane)
    float czm[16];
#pragma unroll
    for (int m = 0; m < 16; ++m) {
        const int k  = (m << 6) | lane;
        const int kr = ((k << 1) | (k >> 9)) & 1023;
        czm[m] = (__popc(k & kr) & 1) ? -1.f : 1.f;
    }

    // phase diagonal d[m] = E(base + sum_q m_q * xv[3-q]) via Gray chain (5 sincos + 15 cmul)
    float fr[4], fi[4];
#pragma unroll
    for (int q = 0; q < 4; ++q) __sincosf(xv[3 - q], &fi[q], &fr[q]);
    float dmr[16], dmi[16];
    __sincosf(base, &dmi[0], &dmr[0]);
#pragma unroll
    for (int m = 1; m < 16; ++m) {
        const int q  = (m & 1) ? 0 : (m & 2) ? 1 : (m & 4) ? 2 : 3;   // ctz(m)
        const int pm = m & (m - 1);
        dmr[m] = dmr[pm] * fr[q] - dmi[pm] * fi[q];
        dmi[m] = dmr[pm] * fi[q] + dmi[pm] * fr[q];
    }
    v2f dr[8], di[8];
#pragma unroll
    for (int p = 0; p < 8; ++p) {
        dr[p] = mk2(dmr[2 * p] * czm[2 * p], dmr[2 * p + 1] * czm[2 * p + 1]);
        di[p] = mk2(dmi[2 * p] * czm[2 * p], dmi[2 * p + 1] * czm[2 * p + 1]);
    }

    // ---- state |0...0> ----
    v2f sr[8], si[8];
#pragma unroll
    for (int p = 0; p < 8; ++p) { sr[p] = sp2(0.f); si[p] = sp2(0.f); }
    if (lane == 0) sr[0].x = 1.f;

    __syncthreads();   // gate table ready (only barrier in the kernel)

#pragma unroll 1
    for (int L = 0; L < 4; ++L) {
        const float* gl = g + L * 80;

        // ---- lane wires j=4..9 (masks 32..1), packed over all 8 v2f pairs ----
#pragma unroll
        for (int j = 4; j < NQ; ++j) {
            const float4 A  = *(const float4*)(gl + j * 8);     // M00r,M00i,M01r,M01i
            const float4 Bq = *(const float4*)(gl + j * 8 + 4); // M10r,M10i,M11r,M11i
            const int  pb  = 9 - j;
            const int  msk = 1 << pb;
            const bool hi  = (lane >> pb) & 1;
            const v2f Ar  = sp2(hi ?  Bq.z :  A.x);
            const v2f Ai  = sp2(hi ?  Bq.w :  A.y);
            const v2f nAi = sp2(hi ? -Bq.w : -A.y);
            const v2f Br  = sp2(hi ?  Bq.x :  A.z);
            const v2f Bi  = sp2(hi ?  Bq.y :  A.w);
            const v2f nBi = sp2(hi ? -Bq.y : -A.w);
#pragma unroll
            for (int p = 0; p < 8; ++p) {
                const v2f qr = shfl2(sr[p], msk);
                const v2f qi = shfl2(si[p], msk);
                v2f tr, ti;
                tr = pkfma(nBi, qi, Br * qr); tr = pkfma(nAi, si[p], tr); tr = pkfma(Ar, sr[p], tr);
                ti = pkfma(Bi,  qr, Br * qi); ti = pkfma(Ai,  sr[p], ti); ti = pkfma(Ar, si[p], ti);
                sr[p] = tr; si[p] = ti;
            }
        }

        // ---- register wires j=2,1,0 (p bits 0,1,2): packed pair gates ----
#pragma unroll
        for (int jj = 0; jj < 3; ++jj) {
            const int j  = 2 - jj;          // j=2 (p bit0), j=1 (p bit1), j=0 (p bit2)
            const int pb = 1 << (2 - j);
            const float4 A  = *(const float4*)(gl + j * 8);
            const float4 Bq = *(const float4*)(gl + j * 8 + 4);
            const v2f g0 = sp2(A.x),  g1 = sp2(A.y),  g2 = sp2(A.z),  g3 = sp2(A.w);
            const v2f g4 = sp2(Bq.x), g5 = sp2(Bq.y), g6 = sp2(Bq.z), g7 = sp2(Bq.w);
#pragma unroll
            for (int p0 = 0; p0 < 8; ++p0) {
                if (p0 & pb) continue;
                const int p1 = p0 | pb;
                const v2f a0r = sr[p0], a0i = si[p0];
                const v2f a1r = sr[p1], a1i = si[p1];
                sr[p0] = pkfma(g0, a0r, pkfma(-g1, a0i, pkfma(g2, a1r, -g3 * a1i)));
                si[p0] = pkfma(g0, a0i, pkfma( g1, a0r, pkfma(g2, a1i,  g3 * a1r)));
                sr[p1] = pkfma(g4, a0r, pkfma(-g5, a0i, pkfma(g6, a1r, -g7 * a1i)));
                si[p1] = pkfma(g4, a0i, pkfma( g5, a0r, pkfma(g6, a1i,  g7 * a1r)));
            }
        }

        // ---- intra-v2f wire j=3 (m bit0): coefficient-swapped packed gate ----
        {
            const float4 A  = *(const float4*)(gl + 3 * 8);
            const float4 Bq = *(const float4*)(gl + 3 * 8 + 4);
            const v2f CAr = mk2(A.x, Bq.z), CAi = mk2(A.y, Bq.w);   // {M00, M11}
            const v2f CBr = mk2(A.z, Bq.x), CBi = mk2(A.w, Bq.y);   // {M01, M10}
            const v2f nCAi = -CAi, nCBi = -CBi;
#pragma unroll
            for (int p = 0; p < 8; ++p) {
                const v2f swr = mk2(sr[p].y, sr[p].x);
                const v2f swi = mk2(si[p].y, si[p].x);
                v2f tr, ti;
                tr = pkfma(nCBi, swi, CBr * swr); tr = pkfma(nCAi, si[p], tr); tr = pkfma(CAr, sr[p], tr);
                ti = pkfma(CBi,  swr, CBr * swi); ti = pkfma(CAi,  sr[p], ti); ti = pkfma(CAr, si[p], ti);
                sr[p] = tr; si[p] = ti;
            }
        }

        // ---- diagonal (CZ * data-reupload phase) for entangling layers only ----
        if (L < 3) {
#pragma unroll
            for (int p = 0; p < 8; ++p) {
                const v2f tr = pkfma(sr[p], dr[p], -(si[p] * di[p]));
                si[p] = pkfma(sr[p], di[p], si[p] * dr[p]);
                sr[p] = tr;
            }
        }
        // L==3: final CZ dropped — |amp|^2 invariant under +-1 diagonal
    }

    // ---- <Z_j> ----
    float pe[8], po[8];
#pragma unroll
    for (int p = 0; p < 8; ++p) {
        const v2f pk = pkfma(sr[p], sr[p], si[p] * si[p]);
        pe[p] = pk.x + pk.y;
        po[p] = pk.x - pk.y;
    }
    float tot = 0.f, t0 = 0.f, t1 = 0.f, t2 = 0.f, t3 = 0.f;
#pragma unroll
    for (int p = 0; p < 8; ++p) {
        tot += pe[p];
        t0  += (p & 4) ? -pe[p] : pe[p];   // wire 0 (m bit 3)
        t1  += (p & 2) ? -pe[p] : pe[p];   // wire 1 (m bit 2)
        t2  += (p & 1) ? -pe[p] : pe[p];   // wire 2 (m bit 1)
        t3  += po[p];                      // wire 3 (m bit 0)
    }
    // plain lane-sums for the m-wires
    v2f u01 = mk2(t0, t1), u23 = mk2(t2, t3);
#pragma unroll
    for (int d = 32; d > 0; d >>= 1) { u01 += shfl2(u01, d); u23 += shfl2(u23, d); }
    // extraction butterfly: D[P] = sum_l (-1)^{lane_P} tot_l  (wire 9-P)
    float Sa = tot, D[6];
#pragma unroll
    for (int P = 0; P < 6; ++P) {
        const float T = __shfl_xor(Sa, 1 << P, 64);
        D[P] = Sa - T;
        Sa   = Sa + T;
    }
#pragma unroll
    for (int P = 0; P < 6; ++P)
#pragma unroll
        for (int Q = P + 1; Q < 6; ++Q) D[P] += __shfl_xor(D[P], 1 << Q, 64);

    if (lane == 0) {
        float* o = out + b * NQ;
        o[0] = u01.x; o[1] = u01.y; o[2] = u23.x; o[3] = u23.y;
        o[4] = D[5];  o[5] = D[4];  o[6] = D[3];  o[7] = D[2];  o[8] = D[1];  o[9] = D[0];
    }
}

extern "C" void kernel_launch(void* const* d_in, const int* in_sizes, int n_in,
                              void* d_out, int out_size, void* d_ws, size_t ws_size,
                              hipStream_t stream) {
    const float* x  = (const float*)d_in[0];   // [B,10] f32
    const float* w1 = (const float*)d_in[1];   // [3,1,10,3] f32
    const float* w2 = (const float*)d_in[2];   // [1,10,3] f32
    float* out = (float*)d_out;                // [B,10] f32
    const int B = in_sizes[0] / NQ;            // 2048
    qlayer_kernel<<<B / 4, 256, 0, stream>>>(x, w1, w2, out);  // 4 waves = 4 elements/block
}

// Round 7
// 23.959 us; speedup vs baseline: 2.6725x; 1.1997x over previous
//
#include <hip/hip_runtime.h>
#include <math.h>

#define NQ 10

typedef float v2f __attribute__((ext_vector_type(2)));

static __device__ __forceinline__ v2f mk2(float a, float b) { v2f r; r.x = a; r.y = b; return r; }
static __device__ __forceinline__ v2f sp2(float a)          { v2f r; r.x = a; r.y = a; return r; }
static __device__ __forceinline__ v2f pkfma(v2f a, v2f b, v2f c) { return __builtin_elementwise_fma(a, b, c); }

// xor-mask lane exchange. Masks 1,2,4,8: DPP (VALU pipe, no LDS). 16: ds_swizzle.
// 32: ds_bpermute via __shfl_xor. All are full-wave permutations, conflict-free.
// DPP direction convention (GCN ISA): row_shl:N -> lane i receives lane i+N;
// row_shr:N -> lane i receives lane i-N. (Round-6 bug: banks swapped for MSK=4.)
template<int MSK>
static __device__ __forceinline__ float lxor(float v) {
    if constexpr (MSK == 1) {        // quad_perm [1,0,3,2]
        const int s = __float_as_int(v);
        return __int_as_float(__builtin_amdgcn_update_dpp(s, s, 0xB1, 0xF, 0xF, false));
    } else if constexpr (MSK == 2) { // quad_perm [2,3,0,1]
        const int s = __float_as_int(v);
        return __int_as_float(__builtin_amdgcn_update_dpp(s, s, 0x4E, 0xF, 0xF, false));
    } else if constexpr (MSK == 4) {
        // banks 0,2 (bit2=0) need lane+4 -> row_shl:4 ; banks 1,3 (bit2=1) need lane-4 -> row_shr:4
        const int s = __float_as_int(v);
        int t = __builtin_amdgcn_update_dpp(s, s, 0x104, 0xF, 0x5, false); // row_shl:4 into banks 0,2
        t     = __builtin_amdgcn_update_dpp(t, s, 0x114, 0xF, 0xA, false); // row_shr:4 into banks 1,3
        return __int_as_float(t);
    } else if constexpr (MSK == 8) { // row_ror:8 == xor8 within a 16-lane row
        const int s = __float_as_int(v);
        return __int_as_float(__builtin_amdgcn_update_dpp(s, s, 0x128, 0xF, 0xF, false));
    } else if constexpr (MSK == 16) {
        return __int_as_float(__builtin_amdgcn_ds_swizzle(__float_as_int(v), 0x401F));
    } else {
        return __shfl_xor(v, 32, 64);
    }
}
template<int MSK>
static __device__ __forceinline__ v2f lxor2(v2f v) { return mk2(lxor<MSK>(v.x), lxor<MSK>(v.y)); }

// One WAVE per batch element (4 elements / 256-thread block; gate table shared in LDS).
// k = m*64 + lane; m = 2*p + e (p = v2f pair index 0..7, e = component).
//   wires 0,1,2 (m bits 3,2,1): packed register-pair gates
//   wire  3     (m bit 0 = e):  intra-v2f gate, coefficient-swapped pkfma
//   wires 4..9  (lane bits 5..0, masks 32..1): lxor exchange gates
// Final CZ layer dropped (|psi|^2 invariant under +-1 diagonal).
__global__ void qlayer_kernel(
    const float* __restrict__ x,    // [B,10]
    const float* __restrict__ w1,   // [3,1,10,3]
    const float* __restrict__ w2,   // [1,10,3]
    float* __restrict__ out)        // [B,10]
{
    __shared__ float g[40 * 8];     // 40 gate matrices {M00,M01,M10,M11}(r,i)

    const int t    = threadIdx.x;
    const int lane = t & 63;
    const int w    = t >> 6;
    const int b    = (blockIdx.x << 2) + w;

    if (t < 40) {
        const int L = t / 10, j = t - L * 10;
        const float* wb = (L < 3) ? (w1 + L * 30 + j * 3) : (w2 + j * 3);
        const float phi = wb[0], th = wb[1], om = wb[2];
        float ct, st, epr, epi, emr, emi;
        __sincosf(0.5f * th, &st, &ct);
        __sincosf(-0.5f * (phi + om), &epi, &epr);
        __sincosf(-0.5f * (phi - om), &emi, &emr);
        float* gp = &g[t * 8];
        gp[0] =  epr * ct; gp[1] =  epi * ct;        // M00
        gp[2] = -emr * st; gp[3] =  emi * st;        // M01 = -conj(em)*s
        gp[4] =  emr * st; gp[5] =  emi * st;        // M10
        gp[6] =  epr * ct; gp[7] = -epi * ct;        // M11 = conj(ep)*c
    }

    // ---- per-lane prologue ----
    float xv[NQ];
#pragma unroll
    for (int j = 0; j < NQ; ++j) xv[j] = x[b * NQ + j];
    float S = 0.f;
#pragma unroll
    for (int j = 0; j < NQ; ++j) S += xv[j];
    float Tlo = 0.f;
#pragma unroll
    for (int p = 0; p < 6; ++p) Tlo += ((lane >> p) & 1) ? xv[9 - p] : 0.f;
    const float base = -0.5f * S + Tlo;

    float czm[16];
#pragma unroll
    for (int m = 0; m < 16; ++m) {
        const int k  = (m << 6) | lane;
        const int kr = ((k << 1) | (k >> 9)) & 1023;
        czm[m] = (__popc(k & kr) & 1) ? -1.f : 1.f;
    }

    // phase diagonal via Gray chain: 5 sincos + 15 cmul
    float fr[4], fi[4];
#pragma unroll
    for (int q = 0; q < 4; ++q) __sincosf(xv[3 - q], &fi[q], &fr[q]);
    float dmr[16], dmi[16];
    __sincosf(base, &dmi[0], &dmr[0]);
#pragma unroll
    for (int m = 1; m < 16; ++m) {
        const int q  = (m & 1) ? 0 : (m & 2) ? 1 : (m & 4) ? 2 : 3;
        const int pm = m & (m - 1);
        dmr[m] = dmr[pm] * fr[q] - dmi[pm] * fi[q];
        dmi[m] = dmr[pm] * fi[q] + dmi[pm] * fr[q];
    }
    v2f dr[8], di[8];
#pragma unroll
    for (int p = 0; p < 8; ++p) {
        dr[p] = mk2(dmr[2 * p] * czm[2 * p], dmr[2 * p + 1] * czm[2 * p + 1]);
        di[p] = mk2(dmi[2 * p] * czm[2 * p], dmi[2 * p + 1] * czm[2 * p + 1]);
    }

    v2f sr[8], si[8];
#pragma unroll
    for (int p = 0; p < 8; ++p) { sr[p] = sp2(0.f); si[p] = sp2(0.f); }
    if (lane == 0) sr[0].x = 1.f;

    __syncthreads();   // gate table ready (only block barrier)

#define LANE_WIRE(J, MSK)                                                                        \
    {                                                                                            \
        const float4 A  = *(const float4*)(gl + (J) * 8);                                        \
        const float4 Bq = *(const float4*)(gl + (J) * 8 + 4);                                    \
        const bool hi  = (lane >> (9 - (J))) & 1;                                                \
        const v2f Ar  = sp2(hi ?  Bq.z :  A.x);                                                  \
        const v2f Ai  = sp2(hi ?  Bq.w :  A.y);                                                  \
        const v2f nAi = -Ai;                                                                     \
        const v2f Br  = sp2(hi ?  Bq.x :  A.z);                                                  \
        const v2f Bi  = sp2(hi ?  Bq.y :  A.w);                                                  \
        const v2f nBi = -Bi;                                                                     \
        _Pragma("unroll")                                                                        \
        for (int p = 0; p < 8; ++p) {                                                            \
            const v2f qr = lxor2<MSK>(sr[p]);                                                    \
            const v2f qi = lxor2<MSK>(si[p]);                                                    \
            v2f tr, ti;                                                                          \
            tr = pkfma(nBi, qi, Br * qr); tr = pkfma(nAi, si[p], tr); tr = pkfma(Ar, sr[p], tr); \
            ti = pkfma(Bi,  qr, Br * qi); ti = pkfma(Ai,  sr[p], ti); ti = pkfma(Ar, si[p], ti); \
            sr[p] = tr; si[p] = ti;                                                              \
        }                                                                                        \
    }

#pragma unroll 1
    for (int L = 0; L < 4; ++L) {
        const float* gl = g + L * 80;

        LANE_WIRE(4, 32)
        LANE_WIRE(5, 16)
        LANE_WIRE(6, 8)
        LANE_WIRE(7, 4)
        LANE_WIRE(8, 2)
        LANE_WIRE(9, 1)

        // register wires j=2,1,0 (p bits 0,1,2)
#pragma unroll
        for (int jj = 0; jj < 3; ++jj) {
            const int j  = 2 - jj;
            const int pb = 1 << (2 - j);
            const float4 A  = *(const float4*)(gl + j * 8);
            const float4 Bq = *(const float4*)(gl + j * 8 + 4);
            const v2f g0 = sp2(A.x),  g1 = sp2(A.y),  g2 = sp2(A.z),  g3 = sp2(A.w);
            const v2f g4 = sp2(Bq.x), g5 = sp2(Bq.y), g6 = sp2(Bq.z), g7 = sp2(Bq.w);
#pragma unroll
            for (int p0 = 0; p0 < 8; ++p0) {
                if (p0 & pb) continue;
                const int p1 = p0 | pb;
                const v2f a0r = sr[p0], a0i = si[p0];
                const v2f a1r = sr[p1], a1i = si[p1];
                sr[p0] = pkfma(g0, a0r, pkfma(-g1, a0i, pkfma(g2, a1r, -g3 * a1i)));
                si[p0] = pkfma(g0, a0i, pkfma( g1, a0r, pkfma(g2, a1i,  g3 * a1r)));
                sr[p1] = pkfma(g4, a0r, pkfma(-g5, a0i, pkfma(g6, a1r, -g7 * a1i)));
                si[p1] = pkfma(g4, a0i, pkfma( g5, a0r, pkfma(g6, a1i,  g7 * a1r)));
            }
        }

        // intra-v2f wire j=3 (m bit 0): coefficient-swapped packed gate
        {
            const float4 A  = *(const float4*)(gl + 3 * 8);
            const float4 Bq = *(const float4*)(gl + 3 * 8 + 4);
            const v2f CAr = mk2(A.x, Bq.z), CAi = mk2(A.y, Bq.w);   // {M00, M11}
            const v2f CBr = mk2(A.z, Bq.x), CBi = mk2(A.w, Bq.y);   // {M01, M10}
            const v2f nCAi = -CAi, nCBi = -CBi;
#pragma unroll
            for (int p = 0; p < 8; ++p) {
                const v2f swr = mk2(sr[p].y, sr[p].x);
                const v2f swi = mk2(si[p].y, si[p].x);
                v2f tr, ti;
                tr = pkfma(nCBi, swi, CBr * swr); tr = pkfma(nCAi, si[p], tr); tr = pkfma(CAr, sr[p], tr);
                ti = pkfma(CBi,  swr, CBr * swi); ti = pkfma(CAi,  sr[p], ti); ti = pkfma(CAr, si[p], ti);
                sr[p] = tr; si[p] = ti;
            }
        }

        // diagonal (CZ * data-reupload) for entangling layers only
        if (L < 3) {
#pragma unroll
            for (int p = 0; p < 8; ++p) {
                const v2f tr = pkfma(sr[p], dr[p], -(si[p] * di[p]));
                si[p] = pkfma(sr[p], di[p], si[p] * dr[p]);
                sr[p] = tr;
            }
        }
    }
#undef LANE_WIRE

    // ---- <Z_j> ----
    float pe[8], po[8];
#pragma unroll
    for (int p = 0; p < 8; ++p) {
        const v2f pk = pkfma(sr[p], sr[p], si[p] * si[p]);
        pe[p] = pk.x + pk.y;
        po[p] = pk.x - pk.y;
    }
    float tot = 0.f, t0 = 0.f, t1 = 0.f, t2 = 0.f, t3 = 0.f;
#pragma unroll
    for (int p = 0; p < 8; ++p) {
        tot += pe[p];
        t0  += (p & 4) ? -pe[p] : pe[p];   // wire 0 (m bit 3)
        t1  += (p & 2) ? -pe[p] : pe[p];   // wire 1 (m bit 2)
        t2  += (p & 1) ? -pe[p] : pe[p];   // wire 2 (m bit 1)
        t3  += po[p];                      // wire 3 (m bit 0)
    }
    v2f u01 = mk2(t0, t1), u23 = mk2(t2, t3);
    u01 += lxor2<1>(u01);  u23 += lxor2<1>(u23);
    u01 += lxor2<2>(u01);  u23 += lxor2<2>(u23);
    u01 += lxor2<4>(u01);  u23 += lxor2<4>(u23);
    u01 += lxor2<8>(u01);  u23 += lxor2<8>(u23);
    u01 += lxor2<16>(u01); u23 += lxor2<16>(u23);
    u01 += lxor2<32>(u01); u23 += lxor2<32>(u23);

    // extraction butterfly for lane wires: D[P] = sum_l (-1)^{lane bit P} tot  (wire 9-P)
    float Sa = tot, T, D0, D1, D2, D3, D4, D5;
    T = lxor<1>(Sa);  D0 = Sa - T; Sa += T;
    T = lxor<2>(Sa);  D1 = Sa - T; Sa += T;
    T = lxor<4>(Sa);  D2 = Sa - T; Sa += T;
    T = lxor<8>(Sa);  D3 = Sa - T; Sa += T;
    T = lxor<16>(Sa); D4 = Sa - T; Sa += T;
    T = lxor<32>(Sa); D5 = Sa - T;
    D0 += lxor<2>(D0); D0 += lxor<4>(D0); D0 += lxor<8>(D0); D0 += lxor<16>(D0); D0 += lxor<32>(D0);
    D1 += lxor<4>(D1); D1 += lxor<8>(D1); D1 += lxor<16>(D1); D1 += lxor<32>(D1);
    D2 += lxor<8>(D2); D2 += lxor<16>(D2); D2 += lxor<32>(D2);
    D3 += lxor<16>(D3); D3 += lxor<32>(D3);
    D4 += lxor<32>(D4);

    if (lane == 0) {
        float* o = out + b * NQ;
        o[0] = u01.x; o[1] = u01.y; o[2] = u23.x; o[3] = u23.y;
        o[4] = D5;    o[5] = D4;    o[6] = D3;    o[7] = D2;    o[8] = D1;    o[9] = D0;
    }
}

extern "C" void kernel_launch(void* const* d_in, const int* in_sizes, int n_in,
                              void* d_out, int out_size, void* d_ws, size_t ws_size,
                              hipStream_t stream) {
    const float* x  = (const float*)d_in[0];   // [B,10] f32
    const float* w1 = (const float*)d_in[1];   // [3,1,10,3] f32
    const float* w2 = (const float*)d_in[2];   // [1,10,3] f32
    float* out = (float*)d_out;                // [B,10] f32
    const int B = in_sizes[0] / NQ;            // 2048
    qlayer_kernel<<<B / 4, 256, 0, stream>>>(x, w1, w2, out);
}